// Round 17
// baseline (166.235 us; speedup 1.0000x reference)
//
#include <hip/hip_runtime.h>
#include <hip/hip_bf16.h>
#include <math.h>

#define NH 16
#define DH 64
#define SEQ 2048
#define EMBED 1024
#define DINNER 1024
#define BATCH 2
#define MTOK 4096   // BATCH*SEQ

typedef __bf16 bf16x8 __attribute__((ext_vector_type(8)));
typedef float  f32x4  __attribute__((ext_vector_type(4)));
typedef float  f32x16 __attribute__((ext_vector_type(16)));
typedef unsigned int u32;

// async global->LDS, 16B per lane (dest = wave-uniform base + lane*16)
__device__ __forceinline__ void gload16(const void* g, void* l) {
    __builtin_amdgcn_global_load_lds((const __attribute__((address_space(1))) void*)g,
                                     (__attribute__((address_space(3))) void*)l, 16, 0, 0);
}

// ---------------------------------------------------------------------------
// f32 -> bf16 flat convert (n divisible by 4)
// ---------------------------------------------------------------------------
__global__ __launch_bounds__(256) void cvt_bf16(
    const float* __restrict__ src, __bf16* __restrict__ dst, int n)
{
    int i = (blockIdx.x * 256 + threadIdx.x) * 4;
    if (i + 3 < n) {
        float4 v = *(const float4*)&src[i];
        dst[i + 0] = (__bf16)v.x;
        dst[i + 1] = (__bf16)v.y;
        dst[i + 2] = (__bf16)v.z;
        dst[i + 3] = (__bf16)v.w;
    }
}

// ---------------------------------------------------------------------------
// 4 weight transposes (all 1024x1024) in one launch: src[R][C] f32 -> dst[C][R] bf16
// ---------------------------------------------------------------------------
__global__ __launch_bounds__(256) void tconv4(
    const float* __restrict__ W0, const float* __restrict__ W1,
    const float* __restrict__ W2, const float* __restrict__ W3,
    __bf16* __restrict__ D0, __bf16* __restrict__ D1,
    __bf16* __restrict__ D2, __bf16* __restrict__ D3)
{
    const int z = blockIdx.z;
    const float* __restrict__ src = (z == 0) ? W0 : (z == 1) ? W1 : (z == 2) ? W2 : W3;
    __bf16* __restrict__ dst      = (z == 0) ? D0 : (z == 1) ? D1 : (z == 2) ? D2 : D3;
    const int R = 1024, C = 1024;

    __shared__ float t[32][33];
    const int c0 = blockIdx.x * 32, r0 = blockIdx.y * 32;
    const int x = threadIdx.x & 31, y = threadIdx.x >> 5;   // 32 x 8
#pragma unroll
    for (int i = 0; i < 4; ++i)
        t[y + 8 * i][x] = src[(size_t)(r0 + y + 8 * i) * C + c0 + x];
    __syncthreads();
#pragma unroll
    for (int i = 0; i < 4; ++i)
        dst[(size_t)(c0 + y + 8 * i) * R + r0 + x] = (__bf16)t[x][y + 8 * i];
}

// ---------------------------------------------------------------------------
// bf16 MFMA GEMM, 128x128 tile, 4 waves (2x2), 16x16x32 MFMA, K-step 32.
// m97 recipe: linear [128][32] LDS staged via global_load_lds width=16.
// A[M][K] bf16, Bt[N][K] bf16 (pre-transposed weights).
// mode3=0: blockIdx.z selects Q/K/V epilogue; mode3=1: fp32 out[m][EMBED]+bias.
//   z=0 -> Q layout [bh][s][d] bf16, scaled by 0.125*log2e (exp2-domain softmax)
//   z=1 -> K layout [bh][s][d] bf16
//   z=2 -> V layout transposed [bh][d][s] bf16 (uint2 store along s)
// ---------------------------------------------------------------------------
#define QSCALE 0.18033688f   // 0.125 * log2(e)

__global__ __launch_bounds__(256) void gemm128(
    const __bf16* __restrict__ A,
    const __bf16* __restrict__ Bt0, const __bf16* __restrict__ Bt1, const __bf16* __restrict__ Bt2,
    const float* __restrict__ b0, const float* __restrict__ b1, const float* __restrict__ b2,
    void* __restrict__ o0, void* __restrict__ o1, void* __restrict__ o2,
    int Kdim, int mode3)
{
    const int z = blockIdx.z;
    const __bf16* __restrict__ Bt = (z == 0) ? Bt0 : (z == 1) ? Bt1 : Bt2;
    const float*  __restrict__ bias = (z == 0) ? b0 : (z == 1) ? b1 : b2;
    void* __restrict__ outp = (z == 0) ? o0 : (z == 1) ? o1 : o2;
    const int mode = mode3 ? 3 : z;

    __shared__ __bf16 As[128 * 32];
    __shared__ __bf16 Bs[128 * 32];

    const int tid  = threadIdx.x;
    const int lane = tid & 63;
    const int wid  = tid >> 6;
    const int wm = wid >> 1, wn = wid & 1;
    const int ls = lane & 15, lg = lane >> 4;
    const int m0 = blockIdx.y * 128, n0 = blockIdx.x * 128;

    const int sr = tid >> 2;           // 0..63
    const int sc = (tid & 3) * 8;      // element col offset (8 bf16 = 16B)

    f32x4 acc[4][4] = {};

    for (int k0 = 0; k0 < Kdim; k0 += 32) {
        gload16(&A [(size_t)(m0 + sr)      * Kdim + k0 + sc], &As[sr * 32 + sc]);
        gload16(&A [(size_t)(m0 + 64 + sr) * Kdim + k0 + sc], &As[(64 + sr) * 32 + sc]);
        gload16(&Bt[(size_t)(n0 + sr)      * Kdim + k0 + sc], &Bs[sr * 32 + sc]);
        gload16(&Bt[(size_t)(n0 + 64 + sr) * Kdim + k0 + sc], &Bs[(64 + sr) * 32 + sc]);
        __syncthreads();

        bf16x8 af[4], bfr[4];
#pragma unroll
        for (int i = 0; i < 4; ++i) {
            af[i]  = *(const bf16x8*)&As[(wm * 64 + i * 16 + ls) * 32 + lg * 8];
            bfr[i] = *(const bf16x8*)&Bs[(wn * 64 + i * 16 + ls) * 32 + lg * 8];
        }
#pragma unroll
        for (int i = 0; i < 4; ++i)
#pragma unroll
            for (int jx = 0; jx < 4; ++jx)
                acc[i][jx] = __builtin_amdgcn_mfma_f32_16x16x32_bf16(af[i], bfr[jx], acc[i][jx], 0, 0, 0);
        __syncthreads();
    }

    // epilogue: C/D layout col = lane&15, row = (lane>>4)*4 + j   [m89-verified]
#pragma unroll
    for (int i = 0; i < 4; ++i) {
#pragma unroll
        for (int jx = 0; jx < 4; ++jx) {
            const int mbase = m0 + wm * 64 + i * 16 + lg * 4;
            const int n = n0 + wn * 64 + jx * 16 + ls;
            if (mode == 3) {
#pragma unroll
                for (int j = 0; j < 4; ++j)
                    ((float*)outp)[(size_t)(mbase + j) * EMBED + n] = acc[i][jx][j] + bias[n];
            } else if (mode == 2) {
                // V^T [bh][d][s]: j-loop contiguous along s -> one 8B store
                const int b = mbase >> 11, s = mbase & 2047;
                const int h = n >> 6, d = n & 63;
                __bf16 t4[4];
#pragma unroll
                for (int j = 0; j < 4; ++j) t4[j] = (__bf16)(acc[i][jx][j] + bias[n]);
                *(uint2*)&((__bf16*)outp)[(((size_t)(b * NH + h) * DH + d) << 11) + s] = *(uint2*)t4;
            } else {
                const float sc2 = (mode == 0) ? QSCALE : 1.0f;
#pragma unroll
                for (int j = 0; j < 4; ++j) {
                    const int m = mbase + j;
                    const int b = m >> 11, s = m & 2047;
                    const int h = n >> 6, d = n & 63;
                    ((__bf16*)outp)[((((size_t)(b * NH + h) << 11) + s) * DH) + d] =
                        (__bf16)((acc[i][jx][j] + bias[n]) * sc2);
                }
            }
        }
    }
}

// ---------------------------------------------------------------------------
// MFMA causal flash attention — ONE WAVE PER BLOCK, barrier-free, frozen-max
// (round-16 math verbatim) + DEPTH-2 PREFETCH via 3-buffer rotation (48 KB).
// Theory: 62-69 us plateau across all structures = per-tile vmcnt stalls;
// 1-tile prefetch (~700 cyc cover) < gload_lds completion (~1500-2000 cyc).
// Depth 2 doubles the cover to ~2 tiles of compute.
// Buffers: buf j = lds + j*16384 (K 8KB | V^T 8KB), tile t uses buf t%3.
// Issue order per tile: K batch then V batch (counting relies on it).
// Prologue stages K0,V0,K1,V1 (32 loads). Steady tile t:
//   vmcnt(24): K_t done (younger: V_t, K_{t+1}, V_{t+1} = 24)
//   ds_read K frags -> QK^T -> issue K_{t+2} into buf (t+2)%3 [if t+2<=nt]
//   softmax (frozen max) -> vmcnt(24) [or 16 on final tile]: V_t done
//   ds_read V frags -> PV -> issue V_{t+2} [if t+2<=nt]
// Over-staged tail tiles read garbage-but-in-workspace bytes (never consumed).
// No lgkm fences needed: the buffer being overwritten was consumed 2 tiles
// ago (its ds_reads completed before those MFMAs issued, compiler-waited).
// Grid = 32 bh x 64 q-tiles = 2048 blocks x 64 thr, heavy-first; same-bh
// blocks stride 32 -> same XCD. Swapped QK^T (S^T=K@Q^T), P->bf16 via
// v_cvt_pk_bf16_f32 + v_permlane32_swap_b32 (T12), XOR-swizzled LDS rows
// (byte^=((row&7)<<4), pre-swizzled global source per rule #21).
// Q,K: [bh][s][d] bf16 (Q pre-scaled 0.125*log2e). Vt: [bh][d][s] bf16.
// ctx: bf16 [b*SEQ+s][h*64+d].
// ---------------------------------------------------------------------------
__global__ __launch_bounds__(64) void attn_mfma(
    const __bf16* __restrict__ Q, const __bf16* __restrict__ K,
    const __bf16* __restrict__ Vt, __bf16* __restrict__ ctx)
{
    __shared__ __bf16 lds[3 * 8192];     // 3 x (K 8KB + V 8KB) = 48 KB

    const int lane = threadIdx.x & 63;
    const int col  = lane & 31;          // q column / fragment row index
    const int hi   = lane >> 5;
    const int bh   = blockIdx.x & 31;    // same-bh blocks stride 32 -> same XCD
    const int qt32 = 63 - (blockIdx.x >> 5);  // reversed: long blocks first
    const int qlo  = qt32 * 32;          // this block's 32 q rows
    const int b = bh >> 4, h = bh & 15;

    const __bf16* __restrict__ Qb = Q + ((size_t)bh << 11) * DH;
    const char* __restrict__ Kg = (const char*)(K  + ((size_t)bh << 11) * DH);
    const char* __restrict__ Vg = (const char*)(Vt + ((size_t)bh << 11) * DH);

    char* const base = (char*)&lds[0];

    // staging (64 lanes): instr i covers tile bytes [i*1024 + lane*16);
    // row = i*8 + (lane>>3); col-byte = (lane&7)*16; row&7 = lane>>3
    const int srow = lane >> 3;                              // 0..7
    const int sswz = ((lane & 7) * 16) ^ (srow << 4);        // pre-swizzled source col
    const int swz  = (col & 7) << 4;

    // Q B-frags (col = q, k-dim = d)
    bf16x8 qf[4];
#pragma unroll
    for (int c = 0; c < 4; ++c)
        qf[c] = *(const bf16x8*)&Qb[(size_t)(qlo + col) * DH + c * 16 + hi * 8];

    const int nt = (qt32 + 2) >> 1;      // 64-key tiles covering keys 0..qlo+31

    // prologue: stage tiles 0 and 1, order K0,V0,K1,V1 (vmcnt counting!)
#pragma unroll
    for (int i = 0; i < 8; ++i)
        gload16(Kg + (size_t)(i * 8 + srow) * 128 + sswz, base + i * 1024 + lane * 16);
#pragma unroll
    for (int i = 0; i < 8; ++i)
        gload16(Vg + (size_t)(i * 8 + srow) * 4096 + sswz, base + 8192 + i * 1024 + lane * 16);
#pragma unroll
    for (int i = 0; i < 8; ++i)
        gload16(Kg + (size_t)(64 + i * 8 + srow) * 128 + sswz, base + 16384 + i * 1024 + lane * 16);
#pragma unroll
    for (int i = 0; i < 8; ++i)
        gload16(Vg + (size_t)(i * 8 + srow) * 4096 + 128 + sswz, base + 16384 + 8192 + i * 1024 + lane * 16);

    f32x16 oT0 = {}, oT1 = {};           // O^T[d][q], d-halves 0-31 / 32-63
    float mrun = 0.f, lrun = 0.f;        // mrun set on tile 0, then FROZEN

    int cur = 0;                         // buffer index of tile t
    for (int t = 0; t < nt; ++t) {
        const int k0 = t * 64;
        int nxt2 = cur + 2; if (nxt2 >= 3) nxt2 -= 3;   // buffer of tile t+2
        const bool more = (t + 2 <= nt);                // stage guard (may over-stage)
        char* ldsK = base + cur * 16384;
        char* ldsV = ldsK + 8192;

        // ---- K_t ready (V_t, K_{t+1}, V_{t+1} = 24 younger ops in flight) ----
        asm volatile("s_waitcnt vmcnt(24)" ::: "memory");

        // ---- K fragments for both 32-key subtiles (swizzled LDS read) ----
        bf16x8 kfa[4], kfb[4];
#pragma unroll
        for (int c = 0; c < 4; ++c) {
            kfa[c] = *(const bf16x8*)(ldsK + (     col) * 128 + ((c * 32 + hi * 16) ^ swz));
            kfb[c] = *(const bf16x8*)(ldsK + (32 + col) * 128 + ((c * 32 + hi * 16) ^ swz));
        }

        // ---- QK^T: two independent S^T[32k][32q] chains ----
        __builtin_amdgcn_s_setprio(1);
        f32x16 sta = {}, stb = {};
#pragma unroll
        for (int c = 0; c < 4; ++c) {
            sta = __builtin_amdgcn_mfma_f32_32x32x16_bf16(kfa[c], qf[c], sta, 0, 0, 0);
            stb = __builtin_amdgcn_mfma_f32_32x32x16_bf16(kfb[c], qf[c], stb, 0, 0, 0);
        }
        __builtin_amdgcn_s_setprio(0);

        // ---- issue K_{t+2} into buf nxt2 (consumed 2 tiles ago; no fence) ----
        if (more) {
            const int kbn = (t + 2) * 64;
#pragma unroll
            for (int i = 0; i < 8; ++i)
                gload16(Kg + (size_t)(kbn + i * 8 + srow) * 128 + sswz,
                        base + nxt2 * 16384 + i * 1024 + lane * 16);
        }

        // ---- causal mask (diagonal-crossing tiles only) ----
        if (k0 + 63 > qlo) {
#pragma unroll
            for (int r = 0; r < 16; ++r) {
                const int krel = (r & 3) + 8 * (r >> 2) + 4 * hi;
                if (k0 + krel > qlo + col)      sta[r] = -INFINITY;
                if (k0 + 32 + krel > qlo + col) stb[r] = -INFINITY;
            }
        }

        // ---- frozen-max softmax: fmax tree ONLY on tile 0 ----
        if (t == 0) {
            float ta = fmaxf(fmaxf(fmaxf(sta[0], sta[1]), fmaxf(sta[2], sta[3])),
                             fmaxf(fmaxf(sta[4], sta[5]), fmaxf(sta[6], sta[7])));
            float tb = fmaxf(fmaxf(fmaxf(sta[8], sta[9]),  fmaxf(sta[10], sta[11])),
                             fmaxf(fmaxf(sta[12], sta[13]), fmaxf(sta[14], sta[15])));
            float tc = fmaxf(fmaxf(fmaxf(stb[0], stb[1]), fmaxf(stb[2], stb[3])),
                             fmaxf(fmaxf(stb[4], stb[5]), fmaxf(stb[6], stb[7])));
            float td = fmaxf(fmaxf(fmaxf(stb[8], stb[9]),  fmaxf(stb[10], stb[11])),
                             fmaxf(fmaxf(stb[12], stb[13]), fmaxf(stb[14], stb[15])));
            float tmax = fmaxf(fmaxf(ta, tb), fmaxf(tc, td));
            tmax = fmaxf(tmax, __shfl_xor(tmax, 32));
            mrun = tmax;                 // finite: every q-row has >=1 unmasked key
        }

        float pa[16], pb[16];
#pragma unroll
        for (int r = 0; r < 16; ++r) { pa[r] = exp2f(sta[r] - mrun); pb[r] = exp2f(stb[r] - mrun); }
        float psa = (((pa[0] + pa[1]) + (pa[2] + pa[3])) + ((pa[4] + pa[5]) + (pa[6] + pa[7])))
                  + (((pa[8] + pa[9]) + (pa[10] + pa[11])) + ((pa[12] + pa[13]) + (pa[14] + pa[15])));
        float psb = (((pb[0] + pb[1]) + (pb[2] + pb[3])) + ((pb[4] + pb[5]) + (pb[6] + pb[7])))
                  + (((pb[8] + pb[9]) + (pb[10] + pb[11])) + ((pb[12] + pb[13]) + (pb[14] + pb[15])));
        float psum = psa + psb;
        psum += __shfl_xor(psum, 32);
        lrun += psum;

        // ---- pack P -> bf16 B-frags (cvt_pk + permlane32_swap), per subtile ----
        u32 wa[8], wb[8];
#pragma unroll
        for (int i = 0; i < 8; ++i) {
            u32 r1, r2;
            asm("v_cvt_pk_bf16_f32 %0, %1, %2" : "=v"(r1) : "v"(pa[2 * i]), "v"(pa[2 * i + 1]));
            asm("v_cvt_pk_bf16_f32 %0, %1, %2" : "=v"(r2) : "v"(pb[2 * i]), "v"(pb[2 * i + 1]));
            wa[i] = r1; wb[i] = r2;
        }
        asm("v_permlane32_swap_b32 %0, %1" : "+v"(wa[0]), "+v"(wa[2]));
        asm("v_permlane32_swap_b32 %0, %1" : "+v"(wa[1]), "+v"(wa[3]));
        asm("v_permlane32_swap_b32 %0, %1" : "+v"(wa[4]), "+v"(wa[6]));
        asm("v_permlane32_swap_b32 %0, %1" : "+v"(wa[5]), "+v"(wa[7]));
        asm("v_permlane32_swap_b32 %0, %1" : "+v"(wb[0]), "+v"(wb[2]));
        asm("v_permlane32_swap_b32 %0, %1" : "+v"(wb[1]), "+v"(wb[3]));
        asm("v_permlane32_swap_b32 %0, %1" : "+v"(wb[4]), "+v"(wb[6]));
        asm("v_permlane32_swap_b32 %0, %1" : "+v"(wb[5]), "+v"(wb[7]));

        union { u32 u4[4]; bf16x8 v; } cA0, cA1, cB0, cB1;
        cA0.u4[0] = wa[0]; cA0.u4[1] = wa[1]; cA0.u4[2] = wa[2]; cA0.u4[3] = wa[3];
        cA1.u4[0] = wa[4]; cA1.u4[1] = wa[5]; cA1.u4[2] = wa[6]; cA1.u4[3] = wa[7];
        cB0.u4[0] = wb[0]; cB0.u4[1] = wb[1]; cB0.u4[2] = wb[2]; cB0.u4[3] = wb[3];
        cB1.u4[0] = wb[4]; cB1.u4[1] = wb[5]; cB1.u4[2] = wb[6]; cB1.u4[3] = wb[7];

        // ---- V_t ready: younger = K_{t+1},V_{t+1},K_{t+2} (24) or 16 at tail ----
        if (more) { asm volatile("s_waitcnt vmcnt(24)" ::: "memory"); }
        else      { asm volatile("s_waitcnt vmcnt(16)" ::: "memory"); }

        // ---- PV from LDS V^T (swizzled read): O^T += V^T[d][k] P^T[k][q] ----
        __builtin_amdgcn_s_setprio(1);
#pragma unroll
        for (int dh = 0; dh < 2; ++dh) {
            bf16x8 v0 = *(const bf16x8*)(ldsV + (dh * 32 + col) * 128 + ((0  + hi * 16) ^ swz));
            bf16x8 v1 = *(const bf16x8*)(ldsV + (dh * 32 + col) * 128 + ((32 + hi * 16) ^ swz));
            bf16x8 v2 = *(const bf16x8*)(ldsV + (dh * 32 + col) * 128 + ((64 + hi * 16) ^ swz));
            bf16x8 v3 = *(const bf16x8*)(ldsV + (dh * 32 + col) * 128 + ((96 + hi * 16) ^ swz));
            f32x16& o = dh ? oT1 : oT0;
            o = __builtin_amdgcn_mfma_f32_32x32x16_bf16(v0, cA0.v, o, 0, 0, 0);
            o = __builtin_amdgcn_mfma_f32_32x32x16_bf16(v1, cA1.v, o, 0, 0, 0);
            o = __builtin_amdgcn_mfma_f32_32x32x16_bf16(v2, cB0.v, o, 0, 0, 0);
            o = __builtin_amdgcn_mfma_f32_32x32x16_bf16(v3, cB1.v, o, 0, 0, 0);
        }
        __builtin_amdgcn_s_setprio(0);

        // ---- issue V_{t+2} into buf nxt2 ----
        if (more) {
            const int kbn = (t + 2) * 64;
#pragma unroll
            for (int i = 0; i < 8; ++i)
                gload16(Vg + (size_t)(i * 8 + srow) * 4096 + (size_t)kbn * 2 + sswz,
                        base + nxt2 * 16384 + 8192 + i * 1024 + lane * 16);
        }

        cur = (cur + 1 == 3) ? 0 : cur + 1;
    }

    // drain any over-staged loads before ending the wave
    asm volatile("s_waitcnt vmcnt(0)" ::: "memory");

    // ---- epilogue: O[q][d] = O^T/l -> ctx[token][h*64+d], 8B packed stores ----
    const float inv = 1.0f / lrun;
    const size_t obase = ((size_t)(b * SEQ + qlo + col)) * DINNER + h * 64;
#pragma unroll
    for (int g = 0; g < 4; ++g) {
        __bf16 t4[4];
#pragma unroll
        for (int j = 0; j < 4; ++j) t4[j] = (__bf16)(oT0[4 * g + j] * inv);
        *(uint2*)&ctx[obase + 8 * g + 4 * hi] = *(uint2*)t4;
#pragma unroll
        for (int j = 0; j < 4; ++j) t4[j] = (__bf16)(oT1[4 * g + j] * inv);
        *(uint2*)&ctx[obase + 32 + 8 * g + 4 * hi] = *(uint2*)t4;
    }
}

// ---------------------------------------------------------------------------
extern "C" void kernel_launch(void* const* d_in, const int* in_sizes, int n_in,
                              void* d_out, int out_size, void* d_ws, size_t ws_size,
                              hipStream_t stream)
{
    const float* X  = (const float*)d_in[0];
    const float* Wq = (const float*)d_in[1];
    const float* bq = (const float*)d_in[2];
    const float* Wk = (const float*)d_in[3];
    const float* bk = (const float*)d_in[4];
    const float* Wv = (const float*)d_in[5];
    const float* bv = (const float*)d_in[6];
    const float* Wo = (const float*)d_in[7];
    const float* bo = (const float*)d_in[8];
    float* out = (float*)d_out;

    // bf16 workspace layout (element offsets, 1 Mi = 1048576)
    __bf16* ws  = (__bf16*)d_ws;
    const size_t MI = 1048576;
    __bf16* Xb   = ws;               // 4 Mi  [4096][1024]
    __bf16* Wtq  = ws + 4  * MI;     // 1 Mi  [1024 n][1024 k]
    __bf16* Wtk  = ws + 5  * MI;
    __bf16* Wtv  = ws + 6  * MI;
    __bf16* Wto  = ws + 7  * MI;
    __bf16* Qb   = ws + 8  * MI;     // 4 Mi  [bh][s][d], pre-scaled 0.125*log2e
    __bf16* Kb   = ws + 12 * MI;     // 4 Mi  [bh][s][d]
    __bf16* Vtb  = ws + 16 * MI;     // 4 Mi  [bh][d][s]
    __bf16* ctxb = ws + 20 * MI;     // 4 Mi  [tok][h*64+d]

    // 1) convert input + 4 weight transposes
    cvt_bf16<<<dim3(MTOK * EMBED / 1024), dim3(256), 0, stream>>>(X, Xb, MTOK * EMBED);
    tconv4<<<dim3(32, 32, 4), dim3(256), 0, stream>>>(Wq, Wk, Wv, Wo, Wtq, Wtk, Wtv, Wto);

    // 2) fused QKV projection (bf16 MFMA GEMM), writes Q(scaled)/K row-major + V transposed
    {
        dim3 grid(DINNER / 128, MTOK / 128, 3), blk(256);
        gemm128<<<grid, blk, 0, stream>>>(Xb, Wtq, Wtk, Wtv, bq, bk, bv,
                                          Qb, Kb, Vtb, EMBED, 0);
    }

    // 3) causal flash attention (1-wave blocks, depth-2 prefetch, frozen-max)
    {
        dim3 grid(32 * (SEQ / 32)), blk(64);
        attn_mfma<<<grid, blk, 0, stream>>>(Qb, Kb, Vtb, ctxb);
    }

    // 4) output projection -> fp32 d_out
    {
        dim3 grid(EMBED / 128, MTOK / 128, 1), blk(256);
        gemm128<<<grid, blk, 0, stream>>>(ctxb, Wto, Wto, Wto, bo, bo, bo,
                                          out, out, out, DINNER, 1);
    }
}

// Round 18
// 145.869 us; speedup vs baseline: 1.1396x; 1.1396x over previous
//
#include <hip/hip_runtime.h>
#include <hip/hip_bf16.h>
#include <math.h>

#define NH 16
#define DH 64
#define SEQ 2048
#define EMBED 1024
#define DINNER 1024
#define BATCH 2
#define MTOK 4096   // BATCH*SEQ

typedef __bf16 bf16x8 __attribute__((ext_vector_type(8)));
typedef float  f32x4  __attribute__((ext_vector_type(4)));
typedef float  f32x16 __attribute__((ext_vector_type(16)));
typedef unsigned int u32;

// async global->LDS, 16B per lane (dest = wave-uniform base + lane*16)
__device__ __forceinline__ void gload16(const void* g, void* l) {
    __builtin_amdgcn_global_load_lds((const __attribute__((address_space(1))) void*)g,
                                     (__attribute__((address_space(3))) void*)l, 16, 0, 0);
}

// ---------------------------------------------------------------------------
// f32 -> bf16 flat convert (n divisible by 4)
// ---------------------------------------------------------------------------
__global__ __launch_bounds__(256) void cvt_bf16(
    const float* __restrict__ src, __bf16* __restrict__ dst, int n)
{
    int i = (blockIdx.x * 256 + threadIdx.x) * 4;
    if (i + 3 < n) {
        float4 v = *(const float4*)&src[i];
        dst[i + 0] = (__bf16)v.x;
        dst[i + 1] = (__bf16)v.y;
        dst[i + 2] = (__bf16)v.z;
        dst[i + 3] = (__bf16)v.w;
    }
}

// ---------------------------------------------------------------------------
// 4 weight transposes (all 1024x1024) in one launch: src[R][C] f32 -> dst[C][R] bf16
// ---------------------------------------------------------------------------
__global__ __launch_bounds__(256) void tconv4(
    const float* __restrict__ W0, const float* __restrict__ W1,
    const float* __restrict__ W2, const float* __restrict__ W3,
    __bf16* __restrict__ D0, __bf16* __restrict__ D1,
    __bf16* __restrict__ D2, __bf16* __restrict__ D3)
{
    const int z = blockIdx.z;
    const float* __restrict__ src = (z == 0) ? W0 : (z == 1) ? W1 : (z == 2) ? W2 : W3;
    __bf16* __restrict__ dst      = (z == 0) ? D0 : (z == 1) ? D1 : (z == 2) ? D2 : D3;
    const int R = 1024, C = 1024;

    __shared__ float t[32][33];
    const int c0 = blockIdx.x * 32, r0 = blockIdx.y * 32;
    const int x = threadIdx.x & 31, y = threadIdx.x >> 5;   // 32 x 8
#pragma unroll
    for (int i = 0; i < 4; ++i)
        t[y + 8 * i][x] = src[(size_t)(r0 + y + 8 * i) * C + c0 + x];
    __syncthreads();
#pragma unroll
    for (int i = 0; i < 4; ++i)
        dst[(size_t)(c0 + y + 8 * i) * R + r0 + x] = (__bf16)t[x][y + 8 * i];
}

// ---------------------------------------------------------------------------
// bf16 MFMA GEMM, 128x64 tile, 4 waves (2 m x 2 n), 16x16x32 MFMA, K-step 32.
// m97 recipe at smaller BN: linear LDS staged via global_load_lds width=16.
// Rationale (r18): m102 shape curve says blocks/CU dominates this regime.
// BN=64 doubles grid: QKV 768->1536 blocks (6/CU), out-proj 256->512 (2/CU).
// Wave tile 64x32 -> acc[4][2]; LDS 12KB/block.
// A[M][K] bf16, Bt[N][K] bf16 (pre-transposed weights).
// mode3=0: blockIdx.z selects Q/K/V epilogue; mode3=1: fp32 out[m][EMBED]+bias.
//   z=0 -> Q layout [bh][s][d] bf16, scaled by 0.125*log2e (exp2-domain softmax)
//   z=1 -> K layout [bh][s][d] bf16
//   z=2 -> V layout transposed [bh][d][s] bf16 (uint2 store along s)
// ---------------------------------------------------------------------------
#define QSCALE 0.18033688f   // 0.125 * log2(e)

__global__ __launch_bounds__(256) void gemm128(
    const __bf16* __restrict__ A,
    const __bf16* __restrict__ Bt0, const __bf16* __restrict__ Bt1, const __bf16* __restrict__ Bt2,
    const float* __restrict__ b0, const float* __restrict__ b1, const float* __restrict__ b2,
    void* __restrict__ o0, void* __restrict__ o1, void* __restrict__ o2,
    int Kdim, int mode3)
{
    const int z = blockIdx.z;
    const __bf16* __restrict__ Bt = (z == 0) ? Bt0 : (z == 1) ? Bt1 : Bt2;
    const float*  __restrict__ bias = (z == 0) ? b0 : (z == 1) ? b1 : b2;
    void* __restrict__ outp = (z == 0) ? o0 : (z == 1) ? o1 : o2;
    const int mode = mode3 ? 3 : z;

    __shared__ __bf16 As[128 * 32];   // 8 KB
    __shared__ __bf16 Bs[64 * 32];    // 4 KB

    const int tid  = threadIdx.x;
    const int lane = tid & 63;
    const int wid  = tid >> 6;
    const int wm = wid >> 1, wn = wid & 1;
    const int ls = lane & 15, lg = lane >> 4;
    const int m0 = blockIdx.y * 128, n0 = blockIdx.x * 64;

    // staging: A = 512 16B-chunks (2/thread), B = 256 16B-chunks (1/thread)
    // chunk i: row = i>>2, col8 = (i&3)*8
    const int ar0 = tid >> 2, ac0 = (tid & 3) * 8;            // A chunk j=0
    const int ar1 = (tid + 256) >> 2, ac1 = ac0;              // A chunk j=1 (rows 64..127)

    f32x4 acc[4][2] = {};

    for (int k0 = 0; k0 < Kdim; k0 += 32) {
        gload16(&A [(size_t)(m0 + ar0) * Kdim + k0 + ac0], &As[ar0 * 32 + ac0]);
        gload16(&A [(size_t)(m0 + ar1) * Kdim + k0 + ac1], &As[ar1 * 32 + ac1]);
        gload16(&Bt[(size_t)(n0 + ar0) * Kdim + k0 + ac0], &Bs[ar0 * 32 + ac0]);  // ar0<64 rows used; ar0>=64 threads reload A rows? no:
        __syncthreads();

        bf16x8 af[4], bfr[2];
#pragma unroll
        for (int i = 0; i < 4; ++i)
            af[i] = *(const bf16x8*)&As[(wm * 64 + i * 16 + ls) * 32 + lg * 8];
#pragma unroll
        for (int j = 0; j < 2; ++j)
            bfr[j] = *(const bf16x8*)&Bs[(wn * 32 + j * 16 + ls) * 32 + lg * 8];
#pragma unroll
        for (int i = 0; i < 4; ++i)
#pragma unroll
            for (int jx = 0; jx < 2; ++jx)
                acc[i][jx] = __builtin_amdgcn_mfma_f32_16x16x32_bf16(af[i], bfr[jx], acc[i][jx], 0, 0, 0);
        __syncthreads();
    }

    // epilogue: C/D layout col = lane&15, row = (lane>>4)*4 + j   [m89-verified]
#pragma unroll
    for (int i = 0; i < 4; ++i) {
#pragma unroll
        for (int jx = 0; jx < 2; ++jx) {
            const int mbase = m0 + wm * 64 + i * 16 + lg * 4;
            const int n = n0 + wn * 32 + jx * 16 + ls;
            if (mode == 3) {
#pragma unroll
                for (int j = 0; j < 4; ++j)
                    ((float*)outp)[(size_t)(mbase + j) * EMBED + n] = acc[i][jx][j] + bias[n];
            } else if (mode == 2) {
                // V^T [bh][d][s]: j-loop contiguous along s -> one 8B store
                const int b = mbase >> 11, s = mbase & 2047;
                const int h = n >> 6, d = n & 63;
                __bf16 t4[4];
#pragma unroll
                for (int j = 0; j < 4; ++j) t4[j] = (__bf16)(acc[i][jx][j] + bias[n]);
                *(uint2*)&((__bf16*)outp)[(((size_t)(b * NH + h) * DH + d) << 11) + s] = *(uint2*)t4;
            } else {
                const float sc2 = (mode == 0) ? QSCALE : 1.0f;
#pragma unroll
                for (int j = 0; j < 4; ++j) {
                    const int m = mbase + j;
                    const int b = m >> 11, s = m & 2047;
                    const int h = n >> 6, d = n & 63;
                    ((__bf16*)outp)[((((size_t)(b * NH + h) << 11) + s) * DH) + d] =
                        (__bf16)((acc[i][jx][j] + bias[n]) * sc2);
                }
            }
        }
    }
}

// ---------------------------------------------------------------------------
// MFMA causal flash attention — ROUND-16 VERBATIM (best measured: 63.1 us).
// One wave per block, barrier-free counted-vmcnt pipeline, frozen-max softmax.
// Grid = 32 bh x 64 q-tiles = 2048 blocks x 64 thr, heavy-first; same-bh
// blocks stride 32 -> same XCD. LDS = 16 KB single buffer (K at 0, V^T at 8K).
// Swapped QK^T (S^T=K@Q^T), P->bf16 via v_cvt_pk_bf16_f32 +
// v_permlane32_swap_b32 (T12), XOR-swizzled LDS rows (pre-swizzled source).
// Q,K: [bh][s][d] bf16 (Q pre-scaled 0.125*log2e). Vt: [bh][d][s] bf16.
// ctx: bf16 [b*SEQ+s][h*64+d].
// ---------------------------------------------------------------------------
__global__ __launch_bounds__(64) void attn_mfma(
    const __bf16* __restrict__ Q, const __bf16* __restrict__ K,
    const __bf16* __restrict__ Vt, __bf16* __restrict__ ctx)
{
    __shared__ __bf16 lds[8192];         // bytes [0,8192)=K tile, [8192,16384)=V^T tile

    const int lane = threadIdx.x & 63;
    const int col  = lane & 31;          // q column / fragment row index
    const int hi   = lane >> 5;
    const int bh   = blockIdx.x & 31;    // same-bh blocks stride 32 -> same XCD
    const int qt32 = 63 - (blockIdx.x >> 5);  // reversed: long blocks first
    const int qlo  = qt32 * 32;          // this block's 32 q rows
    const int b = bh >> 4, h = bh & 15;

    const __bf16* __restrict__ Qb = Q + ((size_t)bh << 11) * DH;
    const char* __restrict__ Kg = (const char*)(K  + ((size_t)bh << 11) * DH);
    const char* __restrict__ Vg = (const char*)(Vt + ((size_t)bh << 11) * DH);

    char* ldsK = (char*)&lds[0];
    char* ldsV = ldsK + 8192;

    // staging (64 lanes): instr i covers tile bytes [i*1024 + lane*16);
    // row = i*8 + (lane>>3); col-byte = (lane&7)*16; row&7 = lane>>3
    const int srow = lane >> 3;                              // 0..7
    const int sswz = ((lane & 7) * 16) ^ (srow << 4);        // pre-swizzled source col
    const int swz  = (col & 7) << 4;

    // Q B-frags (col = q, k-dim = d)
    bf16x8 qf[4];
#pragma unroll
    for (int c = 0; c < 4; ++c)
        qf[c] = *(const bf16x8*)&Qb[(size_t)(qlo + col) * DH + c * 16 + hi * 8];

    const int nt = (qt32 + 2) >> 1;      // 64-key tiles covering keys 0..qlo+31

    // prologue: stage tile 0 (K then V; 8+8 loads in flight)
#pragma unroll
    for (int i = 0; i < 8; ++i)
        gload16(Kg + (size_t)(i * 8 + srow) * 128 + sswz, ldsK + i * 1024 + lane * 16);
#pragma unroll
    for (int i = 0; i < 8; ++i)
        gload16(Vg + (size_t)(i * 8 + srow) * 4096 + sswz, ldsV + i * 1024 + lane * 16);

    f32x16 oT0 = {}, oT1 = {};           // O^T[d][q], d-halves 0-31 / 32-63
    float mrun = 0.f, lrun = 0.f;        // mrun set on tile 0, then FROZEN

    for (int t = 0; t < nt; ++t) {
        const int k0 = t * 64;

        // ---- K_t ready (V_t still in flight) ----
        asm volatile("s_waitcnt vmcnt(8)" ::: "memory");

        // ---- K fragments for both 32-key subtiles (swizzled LDS read) ----
        bf16x8 kfa[4], kfb[4];
#pragma unroll
        for (int c = 0; c < 4; ++c) {
            kfa[c] = *(const bf16x8*)(ldsK + (     col) * 128 + ((c * 32 + hi * 16) ^ swz));
            kfb[c] = *(const bf16x8*)(ldsK + (32 + col) * 128 + ((c * 32 + hi * 16) ^ swz));
        }

        // ---- QK^T: two independent S^T[32k][32q] chains ----
        __builtin_amdgcn_s_setprio(1);
        f32x16 sta = {}, stb = {};
#pragma unroll
        for (int c = 0; c < 4; ++c) {
            sta = __builtin_amdgcn_mfma_f32_32x32x16_bf16(kfa[c], qf[c], sta, 0, 0, 0);
            stb = __builtin_amdgcn_mfma_f32_32x32x16_bf16(kfb[c], qf[c], stb, 0, 0, 0);
        }
        __builtin_amdgcn_s_setprio(0);

        // ---- K-buf dead: fence ds_reads, stage K_{t+1} under the softmax ----
        asm volatile("s_waitcnt lgkmcnt(0)" ::: "memory");
        __builtin_amdgcn_sched_barrier(0);
        if (t + 1 < nt) {
            const int kbn = (t + 1) * 64;
#pragma unroll
            for (int i = 0; i < 8; ++i)
                gload16(Kg + (size_t)(kbn + i * 8 + srow) * 128 + sswz,
                        ldsK + i * 1024 + lane * 16);
        }

        // ---- causal mask (diagonal-crossing tiles only) ----
        if (k0 + 63 > qlo) {
#pragma unroll
            for (int r = 0; r < 16; ++r) {
                const int krel = (r & 3) + 8 * (r >> 2) + 4 * hi;
                if (k0 + krel > qlo + col)      sta[r] = -INFINITY;
                if (k0 + 32 + krel > qlo + col) stb[r] = -INFINITY;
            }
        }

        // ---- frozen-max softmax: fmax tree ONLY on tile 0 ----
        if (t == 0) {
            float ta = fmaxf(fmaxf(fmaxf(sta[0], sta[1]), fmaxf(sta[2], sta[3])),
                             fmaxf(fmaxf(sta[4], sta[5]), fmaxf(sta[6], sta[7])));
            float tb = fmaxf(fmaxf(fmaxf(sta[8], sta[9]),  fmaxf(sta[10], sta[11])),
                             fmaxf(fmaxf(sta[12], sta[13]), fmaxf(sta[14], sta[15])));
            float tc = fmaxf(fmaxf(fmaxf(stb[0], stb[1]), fmaxf(stb[2], stb[3])),
                             fmaxf(fmaxf(stb[4], stb[5]), fmaxf(stb[6], stb[7])));
            float td = fmaxf(fmaxf(fmaxf(stb[8], stb[9]),  fmaxf(stb[10], stb[11])),
                             fmaxf(fmaxf(stb[12], stb[13]), fmaxf(stb[14], stb[15])));
            float tmax = fmaxf(fmaxf(ta, tb), fmaxf(tc, td));
            tmax = fmaxf(tmax, __shfl_xor(tmax, 32));
            mrun = tmax;                 // finite: every q-row has >=1 unmasked key
        }

        float pa[16], pb[16];
#pragma unroll
        for (int r = 0; r < 16; ++r) { pa[r] = exp2f(sta[r] - mrun); pb[r] = exp2f(stb[r] - mrun); }
        float psa = (((pa[0] + pa[1]) + (pa[2] + pa[3])) + ((pa[4] + pa[5]) + (pa[6] + pa[7])))
                  + (((pa[8] + pa[9]) + (pa[10] + pa[11])) + ((pa[12] + pa[13]) + (pa[14] + pa[15])));
        float psb = (((pb[0] + pb[1]) + (pb[2] + pb[3])) + ((pb[4] + pb[5]) + (pb[6] + pb[7])))
                  + (((pb[8] + pb[9]) + (pb[10] + pb[11])) + ((pb[12] + pb[13]) + (pb[14] + pb[15])));
        float psum = psa + psb;
        psum += __shfl_xor(psum, 32);
        lrun += psum;

        // ---- pack P -> bf16 B-frags (cvt_pk + permlane32_swap), per subtile ----
        u32 wa[8], wb[8];
#pragma unroll
        for (int i = 0; i < 8; ++i) {
            u32 r1, r2;
            asm("v_cvt_pk_bf16_f32 %0, %1, %2" : "=v"(r1) : "v"(pa[2 * i]), "v"(pa[2 * i + 1]));
            asm("v_cvt_pk_bf16_f32 %0, %1, %2" : "=v"(r2) : "v"(pb[2 * i]), "v"(pb[2 * i + 1]));
            wa[i] = r1; wb[i] = r2;
        }
        asm("v_permlane32_swap_b32 %0, %1" : "+v"(wa[0]), "+v"(wa[2]));
        asm("v_permlane32_swap_b32 %0, %1" : "+v"(wa[1]), "+v"(wa[3]));
        asm("v_permlane32_swap_b32 %0, %1" : "+v"(wa[4]), "+v"(wa[6]));
        asm("v_permlane32_swap_b32 %0, %1" : "+v"(wa[5]), "+v"(wa[7]));
        asm("v_permlane32_swap_b32 %0, %1" : "+v"(wb[0]), "+v"(wb[2]));
        asm("v_permlane32_swap_b32 %0, %1" : "+v"(wb[1]), "+v"(wb[3]));
        asm("v_permlane32_swap_b32 %0, %1" : "+v"(wb[4]), "+v"(wb[6]));
        asm("v_permlane32_swap_b32 %0, %1" : "+v"(wb[5]), "+v"(wb[7]));

        union { u32 u4[4]; bf16x8 v; } cA0, cA1, cB0, cB1;
        cA0.u4[0] = wa[0]; cA0.u4[1] = wa[1]; cA0.u4[2] = wa[2]; cA0.u4[3] = wa[3];
        cA1.u4[0] = wa[4]; cA1.u4[1] = wa[5]; cA1.u4[2] = wa[6]; cA1.u4[3] = wa[7];
        cB0.u4[0] = wb[0]; cB0.u4[1] = wb[1]; cB0.u4[2] = wb[2]; cB0.u4[3] = wb[3];
        cB1.u4[0] = wb[4]; cB1.u4[1] = wb[5]; cB1.u4[2] = wb[6]; cB1.u4[3] = wb[7];

        // ---- V_t ready (K_{t+1} may stay in flight) ----
        if (t + 1 < nt) { asm volatile("s_waitcnt vmcnt(8)" ::: "memory"); }
        else            { asm volatile("s_waitcnt vmcnt(0)" ::: "memory"); }

        // ---- PV from LDS V^T (swizzled read): O^T += V^T[d][k] P^T[k][q] ----
        __builtin_amdgcn_s_setprio(1);
#pragma unroll
        for (int dh = 0; dh < 2; ++dh) {
            bf16x8 v0 = *(const bf16x8*)(ldsV + (dh * 32 + col) * 128 + ((0  + hi * 16) ^ swz));
            bf16x8 v1 = *(const bf16x8*)(ldsV + (dh * 32 + col) * 128 + ((32 + hi * 16) ^ swz));
            bf16x8 v2 = *(const bf16x8*)(ldsV + (dh * 32 + col) * 128 + ((64 + hi * 16) ^ swz));
            bf16x8 v3 = *(const bf16x8*)(ldsV + (dh * 32 + col) * 128 + ((96 + hi * 16) ^ swz));
            f32x16& o = dh ? oT1 : oT0;
            o = __builtin_amdgcn_mfma_f32_32x32x16_bf16(v0, cA0.v, o, 0, 0, 0);
            o = __builtin_amdgcn_mfma_f32_32x32x16_bf16(v1, cA1.v, o, 0, 0, 0);
            o = __builtin_amdgcn_mfma_f32_32x32x16_bf16(v2, cB0.v, o, 0, 0, 0);
            o = __builtin_amdgcn_mfma_f32_32x32x16_bf16(v3, cB1.v, o, 0, 0, 0);
        }
        __builtin_amdgcn_s_setprio(0);

        // ---- V-buf dead: fence ds_reads, stage V_{t+1} ----
        asm volatile("s_waitcnt lgkmcnt(0)" ::: "memory");
        __builtin_amdgcn_sched_barrier(0);
        if (t + 1 < nt) {
            const int kbn = (t + 1) * 64;
#pragma unroll
            for (int i = 0; i < 8; ++i)
                gload16(Vg + (size_t)(i * 8 + srow) * 4096 + (size_t)kbn * 2 + sswz,
                        ldsV + i * 1024 + lane * 16);
        }
    }

    // ---- epilogue: O[q][d] = O^T/l -> ctx[token][h*64+d], 8B packed stores ----
    const float inv = 1.0f / lrun;
    const size_t base = ((size_t)(b * SEQ + qlo + col)) * DINNER + h * 64;
#pragma unroll
    for (int g = 0; g < 4; ++g) {
        __bf16 t4[4];
#pragma unroll
        for (int j = 0; j < 4; ++j) t4[j] = (__bf16)(oT0[4 * g + j] * inv);
        *(uint2*)&ctx[base + 8 * g + 4 * hi] = *(uint2*)t4;
#pragma unroll
        for (int j = 0; j < 4; ++j) t4[j] = (__bf16)(oT1[4 * g + j] * inv);
        *(uint2*)&ctx[base + 32 + 8 * g + 4 * hi] = *(uint2*)t4;
    }
}

// ---------------------------------------------------------------------------
extern "C" void kernel_launch(void* const* d_in, const int* in_sizes, int n_in,
                              void* d_out, int out_size, void* d_ws, size_t ws_size,
                              hipStream_t stream)
{
    const float* X  = (const float*)d_in[0];
    const float* Wq = (const float*)d_in[1];
    const float* bq = (const float*)d_in[2];
    const float* Wk = (const float*)d_in[3];
    const float* bk = (const float*)d_in[4];
    const float* Wv = (const float*)d_in[5];
    const float* bv = (const float*)d_in[6];
    const float* Wo = (const float*)d_in[7];
    const float* bo = (const float*)d_in[8];
    float* out = (float*)d_out;

    // bf16 workspace layout (element offsets, 1 Mi = 1048576)
    __bf16* ws  = (__bf16*)d_ws;
    const size_t MI = 1048576;
    __bf16* Xb   = ws;               // 4 Mi  [4096][1024]
    __bf16* Wtq  = ws + 4  * MI;     // 1 Mi  [1024 n][1024 k]
    __bf16* Wtk  = ws + 5  * MI;
    __bf16* Wtv  = ws + 6  * MI;
    __bf16* Wto  = ws + 7  * MI;
    __bf16* Qb   = ws + 8  * MI;     // 4 Mi  [bh][s][d], pre-scaled 0.125*log2e
    __bf16* Kb   = ws + 12 * MI;     // 4 Mi  [bh][s][d]
    __bf16* Vtb  = ws + 16 * MI;     // 4 Mi  [bh][d][s]
    __bf16* ctxb = ws + 20 * MI;     // 4 Mi  [tok][h*64+d]

    // 1) convert input + 4 weight transposes
    cvt_bf16<<<dim3(MTOK * EMBED / 1024), dim3(256), 0, stream>>>(X, Xb, MTOK * EMBED);
    tconv4<<<dim3(32, 32, 4), dim3(256), 0, stream>>>(Wq, Wk, Wv, Wo, Wtq, Wtk, Wtv, Wto);

    // 2) fused QKV projection: BN=64 tile -> 16x32x3 = 1536 blocks (6/CU)
    {
        dim3 grid(DINNER / 64, MTOK / 128, 3), blk(256);
        gemm128<<<grid, blk, 0, stream>>>(Xb, Wtq, Wtk, Wtv, bq, bk, bv,
                                          Qb, Kb, Vtb, EMBED, 0);
    }

    // 3) causal flash attention (round-16 verbatim: 1-wave, counted-vmcnt, frozen-max)
    {
        dim3 grid(32 * (SEQ / 32)), blk(64);
        attn_mfma<<<grid, blk, 0, stream>>>(Qb, Kb, Vtb, ctxb);
    }

    // 4) output projection -> fp32 d_out: 16x32 = 512 blocks (2/CU)
    {
        dim3 grid(EMBED / 64, MTOK / 128, 1), blk(256);
        gemm128<<<grid, blk, 0, stream>>>(ctxb, Wto, Wto, Wto, bo, bo, bo,
                                          out, out, out, DINNER, 1);
    }
}

// Round 19
// 145.588 us; speedup vs baseline: 1.1418x; 1.0019x over previous
//
#include <hip/hip_runtime.h>
#include <hip/hip_bf16.h>
#include <math.h>

#define NH 16
#define DH 64
#define SEQ 2048
#define EMBED 1024
#define DINNER 1024
#define BATCH 2
#define MTOK 4096   // BATCH*SEQ

typedef __bf16 bf16x8 __attribute__((ext_vector_type(8)));
typedef float  f32x4  __attribute__((ext_vector_type(4)));
typedef float  f32x16 __attribute__((ext_vector_type(16)));
typedef unsigned int u32;

// async global->LDS, 16B per lane (dest = wave-uniform base + lane*16)
__device__ __forceinline__ void gload16(const void* g, void* l) {
    __builtin_amdgcn_global_load_lds((const __attribute__((address_space(1))) void*)g,
                                     (__attribute__((address_space(3))) void*)l, 16, 0, 0);
}

// ---------------------------------------------------------------------------
// f32 -> bf16 flat convert (n divisible by 4)
// ---------------------------------------------------------------------------
__global__ __launch_bounds__(256) void cvt_bf16(
    const float* __restrict__ src, __bf16* __restrict__ dst, int n)
{
    int i = (blockIdx.x * 256 + threadIdx.x) * 4;
    if (i + 3 < n) {
        float4 v = *(const float4*)&src[i];
        dst[i + 0] = (__bf16)v.x;
        dst[i + 1] = (__bf16)v.y;
        dst[i + 2] = (__bf16)v.z;
        dst[i + 3] = (__bf16)v.w;
    }
}

// ---------------------------------------------------------------------------
// 4 weight transposes (all 1024x1024) in one launch: src[R][C] f32 -> dst[C][R] bf16
// ---------------------------------------------------------------------------
__global__ __launch_bounds__(256) void tconv4(
    const float* __restrict__ W0, const float* __restrict__ W1,
    const float* __restrict__ W2, const float* __restrict__ W3,
    __bf16* __restrict__ D0, __bf16* __restrict__ D1,
    __bf16* __restrict__ D2, __bf16* __restrict__ D3)
{
    const int z = blockIdx.z;
    const float* __restrict__ src = (z == 0) ? W0 : (z == 1) ? W1 : (z == 2) ? W2 : W3;
    __bf16* __restrict__ dst      = (z == 0) ? D0 : (z == 1) ? D1 : (z == 2) ? D2 : D3;
    const int R = 1024, C = 1024;

    __shared__ float t[32][33];
    const int c0 = blockIdx.x * 32, r0 = blockIdx.y * 32;
    const int x = threadIdx.x & 31, y = threadIdx.x >> 5;   // 32 x 8
#pragma unroll
    for (int i = 0; i < 4; ++i)
        t[y + 8 * i][x] = src[(size_t)(r0 + y + 8 * i) * C + c0 + x];
    __syncthreads();
#pragma unroll
    for (int i = 0; i < 4; ++i)
        dst[(size_t)(c0 + y + 8 * i) * R + r0 + x] = (__bf16)t[x][y + 8 * i];
}

// ---------------------------------------------------------------------------
// bf16 MFMA GEMM, 128x64 tile, 4 waves (2 m x 2 n), 16x16x32 MFMA, K-step 32.
// m97 recipe at smaller BN: linear LDS staged via global_load_lds width=16.
// Rationale (r18): m102 shape curve says blocks/CU dominates this regime.
// BN=64 doubles grid: QKV 768->1536 blocks (6/CU), out-proj 256->512 (2/CU).
// Wave tile 64x32 -> acc[4][2]; LDS 12KB/block.
// A[M][K] bf16, Bt[N][K] bf16 (pre-transposed weights).
// mode3=0: blockIdx.z selects Q/K/V epilogue; mode3=1: fp32 out[m][EMBED]+bias.
//   z=0 -> Q layout [bh][s][d] bf16, scaled by 0.125*log2e (exp2-domain softmax)
//   z=1 -> K layout [bh][s][d] bf16
//   z=2 -> V layout transposed [bh][d][s] bf16 (uint2 store along s)
// ---------------------------------------------------------------------------
#define QSCALE 0.18033688f   // 0.125 * log2(e)

__global__ __launch_bounds__(256) void gemm128(
    const __bf16* __restrict__ A,
    const __bf16* __restrict__ Bt0, const __bf16* __restrict__ Bt1, const __bf16* __restrict__ Bt2,
    const float* __restrict__ b0, const float* __restrict__ b1, const float* __restrict__ b2,
    void* __restrict__ o0, void* __restrict__ o1, void* __restrict__ o2,
    int Kdim, int mode3)
{
    const int z = blockIdx.z;
    const __bf16* __restrict__ Bt = (z == 0) ? Bt0 : (z == 1) ? Bt1 : Bt2;
    const float*  __restrict__ bias = (z == 0) ? b0 : (z == 1) ? b1 : b2;
    void* __restrict__ outp = (z == 0) ? o0 : (z == 1) ? o1 : o2;
    const int mode = mode3 ? 3 : z;

    __shared__ __bf16 As[128 * 32];   // 8 KB
    __shared__ __bf16 Bs[64 * 32];    // 4 KB

    const int tid  = threadIdx.x;
    const int lane = tid & 63;
    const int wid  = tid >> 6;
    const int wm = wid >> 1, wn = wid & 1;
    const int ls = lane & 15, lg = lane >> 4;
    const int m0 = blockIdx.y * 128, n0 = blockIdx.x * 64;

    // staging: A = 512 16B-chunks (2/thread), B = 256 16B-chunks (1/thread)
    // chunk i: row = i>>2, col8 = (i&3)*8
    const int ar0 = tid >> 2, ac0 = (tid & 3) * 8;            // A chunk j=0
    const int ar1 = (tid + 256) >> 2, ac1 = ac0;              // A chunk j=1 (rows 64..127)

    f32x4 acc[4][2] = {};

    for (int k0 = 0; k0 < Kdim; k0 += 32) {
        gload16(&A [(size_t)(m0 + ar0) * Kdim + k0 + ac0], &As[ar0 * 32 + ac0]);
        gload16(&A [(size_t)(m0 + ar1) * Kdim + k0 + ac1], &As[ar1 * 32 + ac1]);
        gload16(&Bt[(size_t)(n0 + ar0) * Kdim + k0 + ac0], &Bs[ar0 * 32 + ac0]);  // ar0<64 rows used; ar0>=64 threads reload A rows? no:
        __syncthreads();

        bf16x8 af[4], bfr[2];
#pragma unroll
        for (int i = 0; i < 4; ++i)
            af[i] = *(const bf16x8*)&As[(wm * 64 + i * 16 + ls) * 32 + lg * 8];
#pragma unroll
        for (int j = 0; j < 2; ++j)
            bfr[j] = *(const bf16x8*)&Bs[(wn * 32 + j * 16 + ls) * 32 + lg * 8];
#pragma unroll
        for (int i = 0; i < 4; ++i)
#pragma unroll
            for (int jx = 0; jx < 2; ++jx)
                acc[i][jx] = __builtin_amdgcn_mfma_f32_16x16x32_bf16(af[i], bfr[jx], acc[i][jx], 0, 0, 0);
        __syncthreads();
    }

    // epilogue: C/D layout col = lane&15, row = (lane>>4)*4 + j   [m89-verified]
#pragma unroll
    for (int i = 0; i < 4; ++i) {
#pragma unroll
        for (int jx = 0; jx < 2; ++jx) {
            const int mbase = m0 + wm * 64 + i * 16 + lg * 4;
            const int n = n0 + wn * 32 + jx * 16 + ls;
            if (mode == 3) {
#pragma unroll
                for (int j = 0; j < 4; ++j)
                    ((float*)outp)[(size_t)(mbase + j) * EMBED + n] = acc[i][jx][j] + bias[n];
            } else if (mode == 2) {
                // V^T [bh][d][s]: j-loop contiguous along s -> one 8B store
                const int b = mbase >> 11, s = mbase & 2047;
                const int h = n >> 6, d = n & 63;
                __bf16 t4[4];
#pragma unroll
                for (int j = 0; j < 4; ++j) t4[j] = (__bf16)(acc[i][jx][j] + bias[n]);
                *(uint2*)&((__bf16*)outp)[(((size_t)(b * NH + h) * DH + d) << 11) + s] = *(uint2*)t4;
            } else {
                const float sc2 = (mode == 0) ? QSCALE : 1.0f;
#pragma unroll
                for (int j = 0; j < 4; ++j) {
                    const int m = mbase + j;
                    const int b = m >> 11, s = m & 2047;
                    const int h = n >> 6, d = n & 63;
                    ((__bf16*)outp)[((((size_t)(b * NH + h) << 11) + s) * DH) + d] =
                        (__bf16)((acc[i][jx][j] + bias[n]) * sc2);
                }
            }
        }
    }
}

// ---------------------------------------------------------------------------
// MFMA causal flash attention — ROUND-16 VERBATIM (best measured: 63.1 us).
// One wave per block, barrier-free counted-vmcnt pipeline, frozen-max softmax.
// Grid = 32 bh x 64 q-tiles = 2048 blocks x 64 thr, heavy-first; same-bh
// blocks stride 32 -> same XCD. LDS = 16 KB single buffer (K at 0, V^T at 8K).
// Swapped QK^T (S^T=K@Q^T), P->bf16 via v_cvt_pk_bf16_f32 +
// v_permlane32_swap_b32 (T12), XOR-swizzled LDS rows (pre-swizzled source).
// Q,K: [bh][s][d] bf16 (Q pre-scaled 0.125*log2e). Vt: [bh][d][s] bf16.
// ctx: bf16 [b*SEQ+s][h*64+d].
// ---------------------------------------------------------------------------
__global__ __launch_bounds__(64) void attn_mfma(
    const __bf16* __restrict__ Q, const __bf16* __restrict__ K,
    const __bf16* __restrict__ Vt, __bf16* __restrict__ ctx)
{
    __shared__ __bf16 lds[8192];         // bytes [0,8192)=K tile, [8192,16384)=V^T tile

    const int lane = threadIdx.x & 63;
    const int col  = lane & 31;          // q column / fragment row index
    const int hi   = lane >> 5;
    const int bh   = blockIdx.x & 31;    // same-bh blocks stride 32 -> same XCD
    const int qt32 = 63 - (blockIdx.x >> 5);  // reversed: long blocks first
    const int qlo  = qt32 * 32;          // this block's 32 q rows
    const int b = bh >> 4, h = bh & 15;

    const __bf16* __restrict__ Qb = Q + ((size_t)bh << 11) * DH;
    const char* __restrict__ Kg = (const char*)(K  + ((size_t)bh << 11) * DH);
    const char* __restrict__ Vg = (const char*)(Vt + ((size_t)bh << 11) * DH);

    char* ldsK = (char*)&lds[0];
    char* ldsV = ldsK + 8192;

    // staging (64 lanes): instr i covers tile bytes [i*1024 + lane*16);
    // row = i*8 + (lane>>3); col-byte = (lane&7)*16; row&7 = lane>>3
    const int srow = lane >> 3;                              // 0..7
    const int sswz = ((lane & 7) * 16) ^ (srow << 4);        // pre-swizzled source col
    const int swz  = (col & 7) << 4;

    // Q B-frags (col = q, k-dim = d)
    bf16x8 qf[4];
#pragma unroll
    for (int c = 0; c < 4; ++c)
        qf[c] = *(const bf16x8*)&Qb[(size_t)(qlo + col) * DH + c * 16 + hi * 8];

    const int nt = (qt32 + 2) >> 1;      // 64-key tiles covering keys 0..qlo+31

    // prologue: stage tile 0 (K then V; 8+8 loads in flight)
#pragma unroll
    for (int i = 0; i < 8; ++i)
        gload16(Kg + (size_t)(i * 8 + srow) * 128 + sswz, ldsK + i * 1024 + lane * 16);
#pragma unroll
    for (int i = 0; i < 8; ++i)
        gload16(Vg + (size_t)(i * 8 + srow) * 4096 + sswz, ldsV + i * 1024 + lane * 16);

    f32x16 oT0 = {}, oT1 = {};           // O^T[d][q], d-halves 0-31 / 32-63
    float mrun = 0.f, lrun = 0.f;        // mrun set on tile 0, then FROZEN

    for (int t = 0; t < nt; ++t) {
        const int k0 = t * 64;

        // ---- K_t ready (V_t still in flight) ----
        asm volatile("s_waitcnt vmcnt(8)" ::: "memory");

        // ---- K fragments for both 32-key subtiles (swizzled LDS read) ----
        bf16x8 kfa[4], kfb[4];
#pragma unroll
        for (int c = 0; c < 4; ++c) {
            kfa[c] = *(const bf16x8*)(ldsK + (     col) * 128 + ((c * 32 + hi * 16) ^ swz));
            kfb[c] = *(const bf16x8*)(ldsK + (32 + col) * 128 + ((c * 32 + hi * 16) ^ swz));
        }

        // ---- QK^T: two independent S^T[32k][32q] chains ----
        __builtin_amdgcn_s_setprio(1);
        f32x16 sta = {}, stb = {};
#pragma unroll
        for (int c = 0; c < 4; ++c) {
            sta = __builtin_amdgcn_mfma_f32_32x32x16_bf16(kfa[c], qf[c], sta, 0, 0, 0);
            stb = __builtin_amdgcn_mfma_f32_32x32x16_bf16(kfb[c], qf[c], stb, 0, 0, 0);
        }
        __builtin_amdgcn_s_setprio(0);

        // ---- K-buf dead: fence ds_reads, stage K_{t+1} under the softmax ----
        asm volatile("s_waitcnt lgkmcnt(0)" ::: "memory");
        __builtin_amdgcn_sched_barrier(0);
        if (t + 1 < nt) {
            const int kbn = (t + 1) * 64;
#pragma unroll
            for (int i = 0; i < 8; ++i)
                gload16(Kg + (size_t)(kbn + i * 8 + srow) * 128 + sswz,
                        ldsK + i * 1024 + lane * 16);
        }

        // ---- causal mask (diagonal-crossing tiles only) ----
        if (k0 + 63 > qlo) {
#pragma unroll
            for (int r = 0; r < 16; ++r) {
                const int krel = (r & 3) + 8 * (r >> 2) + 4 * hi;
                if (k0 + krel > qlo + col)      sta[r] = -INFINITY;
                if (k0 + 32 + krel > qlo + col) stb[r] = -INFINITY;
            }
        }

        // ---- frozen-max softmax: fmax tree ONLY on tile 0 ----
        if (t == 0) {
            float ta = fmaxf(fmaxf(fmaxf(sta[0], sta[1]), fmaxf(sta[2], sta[3])),
                             fmaxf(fmaxf(sta[4], sta[5]), fmaxf(sta[6], sta[7])));
            float tb = fmaxf(fmaxf(fmaxf(sta[8], sta[9]),  fmaxf(sta[10], sta[11])),
                             fmaxf(fmaxf(sta[12], sta[13]), fmaxf(sta[14], sta[15])));
            float tc = fmaxf(fmaxf(fmaxf(stb[0], stb[1]), fmaxf(stb[2], stb[3])),
                             fmaxf(fmaxf(stb[4], stb[5]), fmaxf(stb[6], stb[7])));
            float td = fmaxf(fmaxf(fmaxf(stb[8], stb[9]),  fmaxf(stb[10], stb[11])),
                             fmaxf(fmaxf(stb[12], stb[13]), fmaxf(stb[14], stb[15])));
            float tmax = fmaxf(fmaxf(ta, tb), fmaxf(tc, td));
            tmax = fmaxf(tmax, __shfl_xor(tmax, 32));
            mrun = tmax;                 // finite: every q-row has >=1 unmasked key
        }

        float pa[16], pb[16];
#pragma unroll
        for (int r = 0; r < 16; ++r) { pa[r] = exp2f(sta[r] - mrun); pb[r] = exp2f(stb[r] - mrun); }
        float psa = (((pa[0] + pa[1]) + (pa[2] + pa[3])) + ((pa[4] + pa[5]) + (pa[6] + pa[7])))
                  + (((pa[8] + pa[9]) + (pa[10] + pa[11])) + ((pa[12] + pa[13]) + (pa[14] + pa[15])));
        float psb = (((pb[0] + pb[1]) + (pb[2] + pb[3])) + ((pb[4] + pb[5]) + (pb[6] + pb[7])))
                  + (((pb[8] + pb[9]) + (pb[10] + pb[11])) + ((pb[12] + pb[13]) + (pb[14] + pb[15])));
        float psum = psa + psb;
        psum += __shfl_xor(psum, 32);
        lrun += psum;

        // ---- pack P -> bf16 B-frags (cvt_pk + permlane32_swap), per subtile ----
        u32 wa[8], wb[8];
#pragma unroll
        for (int i = 0; i < 8; ++i) {
            u32 r1, r2;
            asm("v_cvt_pk_bf16_f32 %0, %1, %2" : "=v"(r1) : "v"(pa[2 * i]), "v"(pa[2 * i + 1]));
            asm("v_cvt_pk_bf16_f32 %0, %1, %2" : "=v"(r2) : "v"(pb[2 * i]), "v"(pb[2 * i + 1]));
            wa[i] = r1; wb[i] = r2;
        }
        asm("v_permlane32_swap_b32 %0, %1" : "+v"(wa[0]), "+v"(wa[2]));
        asm("v_permlane32_swap_b32 %0, %1" : "+v"(wa[1]), "+v"(wa[3]));
        asm("v_permlane32_swap_b32 %0, %1" : "+v"(wa[4]), "+v"(wa[6]));
        asm("v_permlane32_swap_b32 %0, %1" : "+v"(wa[5]), "+v"(wa[7]));
        asm("v_permlane32_swap_b32 %0, %1" : "+v"(wb[0]), "+v"(wb[2]));
        asm("v_permlane32_swap_b32 %0, %1" : "+v"(wb[1]), "+v"(wb[3]));
        asm("v_permlane32_swap_b32 %0, %1" : "+v"(wb[4]), "+v"(wb[6]));
        asm("v_permlane32_swap_b32 %0, %1" : "+v"(wb[5]), "+v"(wb[7]));

        union { u32 u4[4]; bf16x8 v; } cA0, cA1, cB0, cB1;
        cA0.u4[0] = wa[0]; cA0.u4[1] = wa[1]; cA0.u4[2] = wa[2]; cA0.u4[3] = wa[3];
        cA1.u4[0] = wa[4]; cA1.u4[1] = wa[5]; cA1.u4[2] = wa[6]; cA1.u4[3] = wa[7];
        cB0.u4[0] = wb[0]; cB0.u4[1] = wb[1]; cB0.u4[2] = wb[2]; cB0.u4[3] = wb[3];
        cB1.u4[0] = wb[4]; cB1.u4[1] = wb[5]; cB1.u4[2] = wb[6]; cB1.u4[3] = wb[7];

        // ---- V_t ready (K_{t+1} may stay in flight) ----
        if (t + 1 < nt) { asm volatile("s_waitcnt vmcnt(8)" ::: "memory"); }
        else            { asm volatile("s_waitcnt vmcnt(0)" ::: "memory"); }

        // ---- PV from LDS V^T (swizzled read): O^T += V^T[d][k] P^T[k][q] ----
        __builtin_amdgcn_s_setprio(1);
#pragma unroll
        for (int dh = 0; dh < 2; ++dh) {
            bf16x8 v0 = *(const bf16x8*)(ldsV + (dh * 32 + col) * 128 + ((0  + hi * 16) ^ swz));
            bf16x8 v1 = *(const bf16x8*)(ldsV + (dh * 32 + col) * 128 + ((32 + hi * 16) ^ swz));
            bf16x8 v2 = *(const bf16x8*)(ldsV + (dh * 32 + col) * 128 + ((64 + hi * 16) ^ swz));
            bf16x8 v3 = *(const bf16x8*)(ldsV + (dh * 32 + col) * 128 + ((96 + hi * 16) ^ swz));
            f32x16& o = dh ? oT1 : oT0;
            o = __builtin_amdgcn_mfma_f32_32x32x16_bf16(v0, cA0.v, o, 0, 0, 0);
            o = __builtin_amdgcn_mfma_f32_32x32x16_bf16(v1, cA1.v, o, 0, 0, 0);
            o = __builtin_amdgcn_mfma_f32_32x32x16_bf16(v2, cB0.v, o, 0, 0, 0);
            o = __builtin_amdgcn_mfma_f32_32x32x16_bf16(v3, cB1.v, o, 0, 0, 0);
        }
        __builtin_amdgcn_s_setprio(0);

        // ---- V-buf dead: fence ds_reads, stage V_{t+1} ----
        asm volatile("s_waitcnt lgkmcnt(0)" ::: "memory");
        __builtin_amdgcn_sched_barrier(0);
        if (t + 1 < nt) {
            const int kbn = (t + 1) * 64;
#pragma unroll
            for (int i = 0; i < 8; ++i)
                gload16(Vg + (size_t)(i * 8 + srow) * 4096 + (size_t)kbn * 2 + sswz,
                        ldsV + i * 1024 + lane * 16);
        }
    }

    // ---- epilogue: O[q][d] = O^T/l -> ctx[token][h*64+d], 8B packed stores ----
    const float inv = 1.0f / lrun;
    const size_t base = ((size_t)(b * SEQ + qlo + col)) * DINNER + h * 64;
#pragma unroll
    for (int g = 0; g < 4; ++g) {
        __bf16 t4[4];
#pragma unroll
        for (int j = 0; j < 4; ++j) t4[j] = (__bf16)(oT0[4 * g + j] * inv);
        *(uint2*)&ctx[base + 8 * g + 4 * hi] = *(uint2*)t4;
#pragma unroll
        for (int j = 0; j < 4; ++j) t4[j] = (__bf16)(oT1[4 * g + j] * inv);
        *(uint2*)&ctx[base + 32 + 8 * g + 4 * hi] = *(uint2*)t4;
    }
}

// ---------------------------------------------------------------------------
extern "C" void kernel_launch(void* const* d_in, const int* in_sizes, int n_in,
                              void* d_out, int out_size, void* d_ws, size_t ws_size,
                              hipStream_t stream)
{
    const float* X  = (const float*)d_in[0];
    const float* Wq = (const float*)d_in[1];
    const float* bq = (const float*)d_in[2];
    const float* Wk = (const float*)d_in[3];
    const float* bk = (const float*)d_in[4];
    const float* Wv = (const float*)d_in[5];
    const float* bv = (const float*)d_in[6];
    const float* Wo = (const float*)d_in[7];
    const float* bo = (const float*)d_in[8];
    float* out = (float*)d_out;

    // bf16 workspace layout (element offsets, 1 Mi = 1048576)
    __bf16* ws  = (__bf16*)d_ws;
    const size_t MI = 1048576;
    __bf16* Xb   = ws;               // 4 Mi  [4096][1024]
    __bf16* Wtq  = ws + 4  * MI;     // 1 Mi  [1024 n][1024 k]
    __bf16* Wtk  = ws + 5  * MI;
    __bf16* Wtv  = ws + 6  * MI;
    __bf16* Wto  = ws + 7  * MI;
    __bf16* Qb   = ws + 8  * MI;     // 4 Mi  [bh][s][d], pre-scaled 0.125*log2e
    __bf16* Kb   = ws + 12 * MI;     // 4 Mi  [bh][s][d]
    __bf16* Vtb  = ws + 16 * MI;     // 4 Mi  [bh][d][s]
    __bf16* ctxb = ws + 20 * MI;     // 4 Mi  [tok][h*64+d]

    // 1) convert input + 4 weight transposes
    cvt_bf16<<<dim3(MTOK * EMBED / 1024), dim3(256), 0, stream>>>(X, Xb, MTOK * EMBED);
    tconv4<<<dim3(32, 32, 4), dim3(256), 0, stream>>>(Wq, Wk, Wv, Wo, Wtq, Wtk, Wtv, Wto);

    // 2) fused QKV projection: BN=64 tile -> 16x32x3 = 1536 blocks (6/CU)
    {
        dim3 grid(DINNER / 64, MTOK / 128, 3), blk(256);
        gemm128<<<grid, blk, 0, stream>>>(Xb, Wtq, Wtk, Wtv, bq, bk, bv,
                                          Qb, Kb, Vtb, EMBED, 0);
    }

    // 3) causal flash attention (round-16 verbatim: 1-wave, counted-vmcnt, frozen-max)
    {
        dim3 grid(32 * (SEQ / 32)), blk(64);
        attn_mfma<<<grid, blk, 0, stream>>>(Qb, Kb, Vtb, ctxb);
    }

    // 4) output projection -> fp32 d_out: 16x32 = 512 blocks (2/CU)
    {
        dim3 grid(EMBED / 64, MTOK / 128, 1), blk(256);
        gemm128<<<grid, blk, 0, stream>>>(ctxb, Wto, Wto, Wto, bo, bo, bo,
                                          out, out, out, DINNER, 1);
    }
}

// Round 20
// 129.491 us; speedup vs baseline: 1.2838x; 1.1243x over previous
//
#include <hip/hip_runtime.h>
#include <hip/hip_bf16.h>
#include <math.h>

#define NH 16
#define DH 64
#define SEQ 2048
#define EMBED 1024
#define DINNER 1024
#define BATCH 2
#define MTOK 4096   // BATCH*SEQ

typedef __bf16 bf16x8 __attribute__((ext_vector_type(8)));
typedef float  f32x4  __attribute__((ext_vector_type(4)));
typedef float  f32x16 __attribute__((ext_vector_type(16)));
typedef unsigned int u32;

// async global->LDS, 16B per lane (dest = wave-uniform base + lane*16)
__device__ __forceinline__ void gload16(const void* g, void* l) {
    __builtin_amdgcn_global_load_lds((const __attribute__((address_space(1))) void*)g,
                                     (__attribute__((address_space(3))) void*)l, 16, 0, 0);
}

// ---------------------------------------------------------------------------
// f32 -> bf16 flat convert (n divisible by 4)
// ---------------------------------------------------------------------------
__global__ __launch_bounds__(256) void cvt_bf16(
    const float* __restrict__ src, __bf16* __restrict__ dst, int n)
{
    int i = (blockIdx.x * 256 + threadIdx.x) * 4;
    if (i + 3 < n) {
        float4 v = *(const float4*)&src[i];
        dst[i + 0] = (__bf16)v.x;
        dst[i + 1] = (__bf16)v.y;
        dst[i + 2] = (__bf16)v.z;
        dst[i + 3] = (__bf16)v.w;
    }
}

// ---------------------------------------------------------------------------
// 4 weight transposes (all 1024x1024) in one launch: src[R][C] f32 -> dst[C][R] bf16
// ---------------------------------------------------------------------------
__global__ __launch_bounds__(256) void tconv4(
    const float* __restrict__ W0, const float* __restrict__ W1,
    const float* __restrict__ W2, const float* __restrict__ W3,
    __bf16* __restrict__ D0, __bf16* __restrict__ D1,
    __bf16* __restrict__ D2, __bf16* __restrict__ D3)
{
    const int z = blockIdx.z;
    const float* __restrict__ src = (z == 0) ? W0 : (z == 1) ? W1 : (z == 2) ? W2 : W3;
    __bf16* __restrict__ dst      = (z == 0) ? D0 : (z == 1) ? D1 : (z == 2) ? D2 : D3;
    const int R = 1024, C = 1024;

    __shared__ float t[32][33];
    const int c0 = blockIdx.x * 32, r0 = blockIdx.y * 32;
    const int x = threadIdx.x & 31, y = threadIdx.x >> 5;   // 32 x 8
#pragma unroll
    for (int i = 0; i < 4; ++i)
        t[y + 8 * i][x] = src[(size_t)(r0 + y + 8 * i) * C + c0 + x];
    __syncthreads();
#pragma unroll
    for (int i = 0; i < 4; ++i)
        dst[(size_t)(c0 + y + 8 * i) * R + r0 + x] = (__bf16)t[x][y + 8 * i];
}

// ---------------------------------------------------------------------------
// bf16 MFMA GEMM, 128x128 tile, EIGHT waves (4 m x 2 n), wave-tile 32x64,
// 16x16x32 MFMA, K-step 32. m97 recipe: linear LDS via global_load_lds w=16.
// r20 rationale: r19 showed smaller tiles regress (worse MFMA:stage ratio);
// instead keep the 128^2 tile and DOUBLE waves/block (512 thr) -> out-proj
// goes 1 -> 2 waves/SIMD, QKV up to ~4-5/SIMD (m114 overlap regime).
// Staging: exactly 1x16B chunk/thread for A and B (512 chunks each).
// A[M][K] bf16, Bt[N][K] bf16 (pre-transposed weights).
// mode3=0: blockIdx.z selects Q/K/V epilogue; mode3=1: fp32 out[m][EMBED]+bias.
//   z=0 -> Q layout [bh][s][d] bf16, scaled by 0.125*log2e (exp2-domain softmax)
//   z=1 -> K layout [bh][s][d] bf16
//   z=2 -> V layout transposed [bh][d][s] bf16 (uint2 store along s)
// ---------------------------------------------------------------------------
#define QSCALE 0.18033688f   // 0.125 * log2(e)

__global__ __launch_bounds__(512) void gemm128(
    const __bf16* __restrict__ A,
    const __bf16* __restrict__ Bt0, const __bf16* __restrict__ Bt1, const __bf16* __restrict__ Bt2,
    const float* __restrict__ b0, const float* __restrict__ b1, const float* __restrict__ b2,
    void* __restrict__ o0, void* __restrict__ o1, void* __restrict__ o2,
    int Kdim, int mode3)
{
    const int z = blockIdx.z;
    const __bf16* __restrict__ Bt = (z == 0) ? Bt0 : (z == 1) ? Bt1 : Bt2;
    const float*  __restrict__ bias = (z == 0) ? b0 : (z == 1) ? b1 : b2;
    void* __restrict__ outp = (z == 0) ? o0 : (z == 1) ? o1 : o2;
    const int mode = mode3 ? 3 : z;

    __shared__ __bf16 As[128 * 32];   // 8 KB
    __shared__ __bf16 Bs[128 * 32];   // 8 KB

    const int tid  = threadIdx.x;     // 0..511
    const int lane = tid & 63;
    const int wid  = tid >> 6;        // 0..7
    const int wm = wid >> 1, wn = wid & 1;   // 4 x 2 wave grid
    const int ls = lane & 15, lg = lane >> 4;
    const int m0 = blockIdx.y * 128, n0 = blockIdx.x * 128;

    const int sr = tid >> 2;           // 0..127 (one row per 4 threads)
    const int sc = (tid & 3) * 8;      // element col offset (8 bf16 = 16B)

    f32x4 acc[2][4] = {};

    for (int k0 = 0; k0 < Kdim; k0 += 32) {
        gload16(&A [(size_t)(m0 + sr) * Kdim + k0 + sc], &As[sr * 32 + sc]);
        gload16(&Bt[(size_t)(n0 + sr) * Kdim + k0 + sc], &Bs[sr * 32 + sc]);
        __syncthreads();

        bf16x8 af[2], bfr[4];
#pragma unroll
        for (int i = 0; i < 2; ++i)
            af[i] = *(const bf16x8*)&As[(wm * 32 + i * 16 + ls) * 32 + lg * 8];
#pragma unroll
        for (int jx = 0; jx < 4; ++jx)
            bfr[jx] = *(const bf16x8*)&Bs[(wn * 64 + jx * 16 + ls) * 32 + lg * 8];
#pragma unroll
        for (int i = 0; i < 2; ++i)
#pragma unroll
            for (int jx = 0; jx < 4; ++jx)
                acc[i][jx] = __builtin_amdgcn_mfma_f32_16x16x32_bf16(af[i], bfr[jx], acc[i][jx], 0, 0, 0);
        __syncthreads();
    }

    // epilogue: C/D layout col = lane&15, row = (lane>>4)*4 + j   [m89-verified]
#pragma unroll
    for (int i = 0; i < 2; ++i) {
#pragma unroll
        for (int jx = 0; jx < 4; ++jx) {
            const int mbase = m0 + wm * 32 + i * 16 + lg * 4;
            const int n = n0 + wn * 64 + jx * 16 + ls;
            if (mode == 3) {
#pragma unroll
                for (int j = 0; j < 4; ++j)
                    ((float*)outp)[(size_t)(mbase + j) * EMBED + n] = acc[i][jx][j] + bias[n];
            } else if (mode == 2) {
                // V^T [bh][d][s]: j-loop contiguous along s -> one 8B store
                const int b = mbase >> 11, s = mbase & 2047;
                const int h = n >> 6, d = n & 63;
                __bf16 t4[4];
#pragma unroll
                for (int j = 0; j < 4; ++j) t4[j] = (__bf16)(acc[i][jx][j] + bias[n]);
                *(uint2*)&((__bf16*)outp)[(((size_t)(b * NH + h) * DH + d) << 11) + s] = *(uint2*)t4;
            } else {
                const float sc2 = (mode == 0) ? QSCALE : 1.0f;
#pragma unroll
                for (int j = 0; j < 4; ++j) {
                    const int m = mbase + j;
                    const int b = m >> 11, s = m & 2047;
                    const int h = n >> 6, d = n & 63;
                    ((__bf16*)outp)[((((size_t)(b * NH + h) << 11) + s) * DH) + d] =
                        (__bf16)((acc[i][jx][j] + bias[n]) * sc2);
                }
            }
        }
    }
}

// ---------------------------------------------------------------------------
// MFMA causal flash attention — ROUND-16 VERBATIM (best measured: 63.0 us).
// One wave per block, barrier-free counted-vmcnt pipeline, frozen-max softmax.
// Grid = 32 bh x 64 q-tiles = 2048 blocks x 64 thr, heavy-first; same-bh
// blocks stride 32 -> same XCD. LDS = 16 KB single buffer (K at 0, V^T at 8K).
// Swapped QK^T (S^T=K@Q^T), P->bf16 via v_cvt_pk_bf16_f32 +
// v_permlane32_swap_b32 (T12), XOR-swizzled LDS rows (pre-swizzled source).
// Q,K: [bh][s][d] bf16 (Q pre-scaled 0.125*log2e). Vt: [bh][d][s] bf16.
// ctx: bf16 [b*SEQ+s][h*64+d].
// ---------------------------------------------------------------------------
__global__ __launch_bounds__(64) void attn_mfma(
    const __bf16* __restrict__ Q, const __bf16* __restrict__ K,
    const __bf16* __restrict__ Vt, __bf16* __restrict__ ctx)
{
    __shared__ __bf16 lds[8192];         // bytes [0,8192)=K tile, [8192,16384)=V^T tile

    const int lane = threadIdx.x & 63;
    const int col  = lane & 31;          // q column / fragment row index
    const int hi   = lane >> 5;
    const int bh   = blockIdx.x & 31;    // same-bh blocks stride 32 -> same XCD
    const int qt32 = 63 - (blockIdx.x >> 5);  // reversed: long blocks first
    const int qlo  = qt32 * 32;          // this block's 32 q rows
    const int b = bh >> 4, h = bh & 15;

    const __bf16* __restrict__ Qb = Q + ((size_t)bh << 11) * DH;
    const char* __restrict__ Kg = (const char*)(K  + ((size_t)bh << 11) * DH);
    const char* __restrict__ Vg = (const char*)(Vt + ((size_t)bh << 11) * DH);

    char* ldsK = (char*)&lds[0];
    char* ldsV = ldsK + 8192;

    // staging (64 lanes): instr i covers tile bytes [i*1024 + lane*16);
    // row = i*8 + (lane>>3); col-byte = (lane&7)*16; row&7 = lane>>3
    const int srow = lane >> 3;                              // 0..7
    const int sswz = ((lane & 7) * 16) ^ (srow << 4);        // pre-swizzled source col
    const int swz  = (col & 7) << 4;

    // Q B-frags (col = q, k-dim = d)
    bf16x8 qf[4];
#pragma unroll
    for (int c = 0; c < 4; ++c)
        qf[c] = *(const bf16x8*)&Qb[(size_t)(qlo + col) * DH + c * 16 + hi * 8];

    const int nt = (qt32 + 2) >> 1;      // 64-key tiles covering keys 0..qlo+31

    // prologue: stage tile 0 (K then V; 8+8 loads in flight)
#pragma unroll
    for (int i = 0; i < 8; ++i)
        gload16(Kg + (size_t)(i * 8 + srow) * 128 + sswz, ldsK + i * 1024 + lane * 16);
#pragma unroll
    for (int i = 0; i < 8; ++i)
        gload16(Vg + (size_t)(i * 8 + srow) * 4096 + sswz, ldsV + i * 1024 + lane * 16);

    f32x16 oT0 = {}, oT1 = {};           // O^T[d][q], d-halves 0-31 / 32-63
    float mrun = 0.f, lrun = 0.f;        // mrun set on tile 0, then FROZEN

    for (int t = 0; t < nt; ++t) {
        const int k0 = t * 64;

        // ---- K_t ready (V_t still in flight) ----
        asm volatile("s_waitcnt vmcnt(8)" ::: "memory");

        // ---- K fragments for both 32-key subtiles (swizzled LDS read) ----
        bf16x8 kfa[4], kfb[4];
#pragma unroll
        for (int c = 0; c < 4; ++c) {
            kfa[c] = *(const bf16x8*)(ldsK + (     col) * 128 + ((c * 32 + hi * 16) ^ swz));
            kfb[c] = *(const bf16x8*)(ldsK + (32 + col) * 128 + ((c * 32 + hi * 16) ^ swz));
        }

        // ---- QK^T: two independent S^T[32k][32q] chains ----
        __builtin_amdgcn_s_setprio(1);
        f32x16 sta = {}, stb = {};
#pragma unroll
        for (int c = 0; c < 4; ++c) {
            sta = __builtin_amdgcn_mfma_f32_32x32x16_bf16(kfa[c], qf[c], sta, 0, 0, 0);
            stb = __builtin_amdgcn_mfma_f32_32x32x16_bf16(kfb[c], qf[c], stb, 0, 0, 0);
        }
        __builtin_amdgcn_s_setprio(0);

        // ---- K-buf dead: fence ds_reads, stage K_{t+1} under the softmax ----
        asm volatile("s_waitcnt lgkmcnt(0)" ::: "memory");
        __builtin_amdgcn_sched_barrier(0);
        if (t + 1 < nt) {
            const int kbn = (t + 1) * 64;
#pragma unroll
            for (int i = 0; i < 8; ++i)
                gload16(Kg + (size_t)(kbn + i * 8 + srow) * 128 + sswz,
                        ldsK + i * 1024 + lane * 16);
        }

        // ---- causal mask (diagonal-crossing tiles only) ----
        if (k0 + 63 > qlo) {
#pragma unroll
            for (int r = 0; r < 16; ++r) {
                const int krel = (r & 3) + 8 * (r >> 2) + 4 * hi;
                if (k0 + krel > qlo + col)      sta[r] = -INFINITY;
                if (k0 + 32 + krel > qlo + col) stb[r] = -INFINITY;
            }
        }

        // ---- frozen-max softmax: fmax tree ONLY on tile 0 ----
        if (t == 0) {
            float ta = fmaxf(fmaxf(fmaxf(sta[0], sta[1]), fmaxf(sta[2], sta[3])),
                             fmaxf(fmaxf(sta[4], sta[5]), fmaxf(sta[6], sta[7])));
            float tb = fmaxf(fmaxf(fmaxf(sta[8], sta[9]),  fmaxf(sta[10], sta[11])),
                             fmaxf(fmaxf(sta[12], sta[13]), fmaxf(sta[14], sta[15])));
            float tc = fmaxf(fmaxf(fmaxf(stb[0], stb[1]), fmaxf(stb[2], stb[3])),
                             fmaxf(fmaxf(stb[4], stb[5]), fmaxf(stb[6], stb[7])));
            float td = fmaxf(fmaxf(fmaxf(stb[8], stb[9]),  fmaxf(stb[10], stb[11])),
                             fmaxf(fmaxf(stb[12], stb[13]), fmaxf(stb[14], stb[15])));
            float tmax = fmaxf(fmaxf(ta, tb), fmaxf(tc, td));
            tmax = fmaxf(tmax, __shfl_xor(tmax, 32));
            mrun = tmax;                 // finite: every q-row has >=1 unmasked key
        }

        float pa[16], pb[16];
#pragma unroll
        for (int r = 0; r < 16; ++r) { pa[r] = exp2f(sta[r] - mrun); pb[r] = exp2f(stb[r] - mrun); }
        float psa = (((pa[0] + pa[1]) + (pa[2] + pa[3])) + ((pa[4] + pa[5]) + (pa[6] + pa[7])))
                  + (((pa[8] + pa[9]) + (pa[10] + pa[11])) + ((pa[12] + pa[13]) + (pa[14] + pa[15])));
        float psb = (((pb[0] + pb[1]) + (pb[2] + pb[3])) + ((pb[4] + pb[5]) + (pb[6] + pb[7])))
                  + (((pb[8] + pb[9]) + (pb[10] + pb[11])) + ((pb[12] + pb[13]) + (pb[14] + pb[15])));
        float psum = psa + psb;
        psum += __shfl_xor(psum, 32);
        lrun += psum;

        // ---- pack P -> bf16 B-frags (cvt_pk + permlane32_swap), per subtile ----
        u32 wa[8], wb[8];
#pragma unroll
        for (int i = 0; i < 8; ++i) {
            u32 r1, r2;
            asm("v_cvt_pk_bf16_f32 %0, %1, %2" : "=v"(r1) : "v"(pa[2 * i]), "v"(pa[2 * i + 1]));
            asm("v_cvt_pk_bf16_f32 %0, %1, %2" : "=v"(r2) : "v"(pb[2 * i]), "v"(pb[2 * i + 1]));
            wa[i] = r1; wb[i] = r2;
        }
        asm("v_permlane32_swap_b32 %0, %1" : "+v"(wa[0]), "+v"(wa[2]));
        asm("v_permlane32_swap_b32 %0, %1" : "+v"(wa[1]), "+v"(wa[3]));
        asm("v_permlane32_swap_b32 %0, %1" : "+v"(wa[4]), "+v"(wa[6]));
        asm("v_permlane32_swap_b32 %0, %1" : "+v"(wa[5]), "+v"(wa[7]));
        asm("v_permlane32_swap_b32 %0, %1" : "+v"(wb[0]), "+v"(wb[2]));
        asm("v_permlane32_swap_b32 %0, %1" : "+v"(wb[1]), "+v"(wb[3]));
        asm("v_permlane32_swap_b32 %0, %1" : "+v"(wb[4]), "+v"(wb[6]));
        asm("v_permlane32_swap_b32 %0, %1" : "+v"(wb[5]), "+v"(wb[7]));

        union { u32 u4[4]; bf16x8 v; } cA0, cA1, cB0, cB1;
        cA0.u4[0] = wa[0]; cA0.u4[1] = wa[1]; cA0.u4[2] = wa[2]; cA0.u4[3] = wa[3];
        cA1.u4[0] = wa[4]; cA1.u4[1] = wa[5]; cA1.u4[2] = wa[6]; cA1.u4[3] = wa[7];
        cB0.u4[0] = wb[0]; cB0.u4[1] = wb[1]; cB0.u4[2] = wb[2]; cB0.u4[3] = wb[3];
        cB1.u4[0] = wb[4]; cB1.u4[1] = wb[5]; cB1.u4[2] = wb[6]; cB1.u4[3] = wb[7];

        // ---- V_t ready (K_{t+1} may stay in flight) ----
        if (t + 1 < nt) { asm volatile("s_waitcnt vmcnt(8)" ::: "memory"); }
        else            { asm volatile("s_waitcnt vmcnt(0)" ::: "memory"); }

        // ---- PV from LDS V^T (swizzled read): O^T += V^T[d][k] P^T[k][q] ----
        __builtin_amdgcn_s_setprio(1);
#pragma unroll
        for (int dh = 0; dh < 2; ++dh) {
            bf16x8 v0 = *(const bf16x8*)(ldsV + (dh * 32 + col) * 128 + ((0  + hi * 16) ^ swz));
            bf16x8 v1 = *(const bf16x8*)(ldsV + (dh * 32 + col) * 128 + ((32 + hi * 16) ^ swz));
            bf16x8 v2 = *(const bf16x8*)(ldsV + (dh * 32 + col) * 128 + ((64 + hi * 16) ^ swz));
            bf16x8 v3 = *(const bf16x8*)(ldsV + (dh * 32 + col) * 128 + ((96 + hi * 16) ^ swz));
            f32x16& o = dh ? oT1 : oT0;
            o = __builtin_amdgcn_mfma_f32_32x32x16_bf16(v0, cA0.v, o, 0, 0, 0);
            o = __builtin_amdgcn_mfma_f32_32x32x16_bf16(v1, cA1.v, o, 0, 0, 0);
            o = __builtin_amdgcn_mfma_f32_32x32x16_bf16(v2, cB0.v, o, 0, 0, 0);
            o = __builtin_amdgcn_mfma_f32_32x32x16_bf16(v3, cB1.v, o, 0, 0, 0);
        }
        __builtin_amdgcn_s_setprio(0);

        // ---- V-buf dead: fence ds_reads, stage V_{t+1} ----
        asm volatile("s_waitcnt lgkmcnt(0)" ::: "memory");
        __builtin_amdgcn_sched_barrier(0);
        if (t + 1 < nt) {
            const int kbn = (t + 1) * 64;
#pragma unroll
            for (int i = 0; i < 8; ++i)
                gload16(Vg + (size_t)(i * 8 + srow) * 4096 + (size_t)kbn * 2 + sswz,
                        ldsV + i * 1024 + lane * 16);
        }
    }

    // ---- epilogue: O[q][d] = O^T/l -> ctx[token][h*64+d], 8B packed stores ----
    const float inv = 1.0f / lrun;
    const size_t base = ((size_t)(b * SEQ + qlo + col)) * DINNER + h * 64;
#pragma unroll
    for (int g = 0; g < 4; ++g) {
        __bf16 t4[4];
#pragma unroll
        for (int j = 0; j < 4; ++j) t4[j] = (__bf16)(oT0[4 * g + j] * inv);
        *(uint2*)&ctx[base + 8 * g + 4 * hi] = *(uint2*)t4;
#pragma unroll
        for (int j = 0; j < 4; ++j) t4[j] = (__bf16)(oT1[4 * g + j] * inv);
        *(uint2*)&ctx[base + 32 + 8 * g + 4 * hi] = *(uint2*)t4;
    }
}

// ---------------------------------------------------------------------------
extern "C" void kernel_launch(void* const* d_in, const int* in_sizes, int n_in,
                              void* d_out, int out_size, void* d_ws, size_t ws_size,
                              hipStream_t stream)
{
    const float* X  = (const float*)d_in[0];
    const float* Wq = (const float*)d_in[1];
    const float* bq = (const float*)d_in[2];
    const float* Wk = (const float*)d_in[3];
    const float* bk = (const float*)d_in[4];
    const float* Wv = (const float*)d_in[5];
    const float* bv = (const float*)d_in[6];
    const float* Wo = (const float*)d_in[7];
    const float* bo = (const float*)d_in[8];
    float* out = (float*)d_out;

    // bf16 workspace layout (element offsets, 1 Mi = 1048576)
    __bf16* ws  = (__bf16*)d_ws;
    const size_t MI = 1048576;
    __bf16* Xb   = ws;               // 4 Mi  [4096][1024]
    __bf16* Wtq  = ws + 4  * MI;     // 1 Mi  [1024 n][1024 k]
    __bf16* Wtk  = ws + 5  * MI;
    __bf16* Wtv  = ws + 6  * MI;
    __bf16* Wto  = ws + 7  * MI;
    __bf16* Qb   = ws + 8  * MI;     // 4 Mi  [bh][s][d], pre-scaled 0.125*log2e
    __bf16* Kb   = ws + 12 * MI;     // 4 Mi  [bh][s][d]
    __bf16* Vtb  = ws + 16 * MI;     // 4 Mi  [bh][d][s]
    __bf16* ctxb = ws + 20 * MI;     // 4 Mi  [tok][h*64+d]

    // 1) convert input + 4 weight transposes
    cvt_bf16<<<dim3(MTOK * EMBED / 1024), dim3(256), 0, stream>>>(X, Xb, MTOK * EMBED);
    tconv4<<<dim3(32, 32, 4), dim3(256), 0, stream>>>(Wq, Wk, Wv, Wo, Wtq, Wtk, Wtv, Wto);

    // 2) fused QKV projection: 128^2 tile, 8 waves -> 768 blocks x 512 thr
    {
        dim3 grid(DINNER / 128, MTOK / 128, 3), blk(512);
        gemm128<<<grid, blk, 0, stream>>>(Xb, Wtq, Wtk, Wtv, bq, bk, bv,
                                          Qb, Kb, Vtb, EMBED, 0);
    }

    // 3) causal flash attention (round-16 verbatim: 1-wave, counted-vmcnt, frozen-max)
    {
        dim3 grid(32 * (SEQ / 32)), blk(64);
        attn_mfma<<<grid, blk, 0, stream>>>(Qb, Kb, Vtb, ctxb);
    }

    // 4) output projection -> fp32 d_out: 128^2 tile, 8 waves -> 256 blocks x 512 thr
    {
        dim3 grid(EMBED / 128, MTOK / 128, 1), blk(512);
        gemm128<<<grid, blk, 0, stream>>>(ctxb, Wto, Wto, Wto, bo, bo, bo,
                                          out, out, out, DINNER, 1);
    }
}